// Round 4
// baseline (472.996 us; speedup 1.0000x reference)
//
#include <hip/hip_runtime.h>
#include <hip/hip_bf16.h>
#include <math.h>

typedef unsigned short u16;
typedef short s16x8 __attribute__((ext_vector_type(8)));
typedef float f32x4 __attribute__((ext_vector_type(4)));

// K-position interleave within a 32-wide k-tile: lane group g reads 16B = k [4g..4g+3, 16+4g..16+4g+3]
__device__ __host__ __forceinline__ int KP(int k) {
    return ((k & 12) << 1) | (((k >> 4) & 1) << 2) | (k & 3);
}
// bank-conflict swizzle baked into global blocked layout (u16 index within a tile).
// Reads at rows r0+lr land 8 lanes per 16B-slot => conflict-free ds_read_b128.
__device__ __host__ __forceinline__ int SWZ(int row, int e) {
    return (row * 32 + e) ^ ((row & 15) << 3);
}

__device__ __forceinline__ float geluf(float x) {
    return 0.5f * x * (1.0f + erff(x * 0.70710678118654752f));
}
__device__ __forceinline__ u16 f2bf(float f) {
    unsigned u = __builtin_bit_cast(unsigned, f);
    return (u16)((u + 0x7fffu + ((u >> 16) & 1u)) >> 16);
}
__device__ __forceinline__ float bf2f(u16 h) {
    return __builtin_bit_cast(float, ((unsigned)h) << 16);
}
__device__ __forceinline__ void async_copy16(const u16* gsrc, u16* ldst) {
    __builtin_amdgcn_global_load_lds((const __attribute__((address_space(1))) void*)gsrc,
                                     (__attribute__((address_space(3))) void*)ldst, 16, 0, 0);
}
__device__ __forceinline__ float wave_reduce_sum(float v) {
    #pragma unroll
    for (int m = 32; m >= 1; m >>= 1) v += __shfl_xor(v, m, 64);
    return v;
}

#define MFMA(a, b, c) __builtin_amdgcn_mfma_f32_16x16x32_bf16(a, b, c, 0, 0, 0)

// ---------- prep: W[K][N] fp32 -> blocked bf16 tiles [(cb*K/32+kt)][CB rows][32], swizzled
__global__ __launch_bounds__(256) void prep_w(const float* __restrict__ W, u16* __restrict__ out,
                                              int K, int N, int CB) {
    int idx = blockIdx.x * 256 + threadIdx.x;
    if (idx >= K * N) return;
    int k = idx / N, col = idx % N;
    int cb = col / CB, ci = col % CB, kt = k >> 5, ki = k & 31;
    out[(size_t)(cb * (K >> 5) + kt) * (CB * 32) + SWZ(ci, KP(ki))] = f2bf(W[idx]);
}

// ---------- prep W1 feature rows (128..511) -> tiles [ks=f*4+dt][256 rows][32], swizzled
__global__ __launch_bounds__(256) void prep_w1(const float* __restrict__ W1, u16* __restrict__ out) {
    int idx = blockIdx.x * 256 + threadIdx.x;   // over 384*256
    if (idx >= 384 * 256) return;
    int k = idx / 256 + 128, col = idx % 256;
    int f = (k >> 7) - 1, dt = (k >> 5) & 3, ki = k & 31;
    out[(size_t)(f * 4 + dt) * 8192 + SWZ(col, KP(ki))] = f2bf(W1[(size_t)k * 256 + col]);
}

// ---------- nf = LN(ent + role_emb[roles]) -> blocked bf16 tiles [(row>>7)*24+kt][128][32], swizzled
__global__ __launch_bounds__(256) void nf_ln_kernel(
    const float* __restrict__ ent, const int* __restrict__ roles,
    const float* __restrict__ role_emb, const float* __restrict__ g,
    const float* __restrict__ bta, u16* __restrict__ nfb)
{
    int wave = threadIdx.x >> 6, lane = threadIdx.x & 63;
    int row = blockIdx.x * 4 + wave;
    const float* er = ent + (size_t)row * 768;
    const float* rr = role_emb + roles[row] * 768;
    float x[12]; float s = 0.f, s2 = 0.f;
    #pragma unroll
    for (int i = 0; i < 12; ++i) {
        x[i] = er[i * 64 + lane] + rr[i * 64 + lane];
        s += x[i]; s2 += x[i] * x[i];
    }
    s = wave_reduce_sum(s); s2 = wave_reduce_sum(s2);
    float mu = s * (1.f / 768.f);
    float var = s2 * (1.f / 768.f) - mu * mu;
    float rs = rsqrtf(var + 1e-5f);
    size_t rb = (size_t)(row >> 7) * 24;
    int rin = row & 127;
    #pragma unroll
    for (int i = 0; i < 12; ++i) {
        int k = i * 64 + lane;
        float v = (x[i] - mu) * rs * g[k] + bta[k];
        nfb[(rb + (k >> 5)) * 4096 + SWZ(rin, KP(k & 31))] = f2bf(v);
    }
}

// ---------- q = gelu(q_emb @ Wq + bq) -> bf16 [64][1024] row-major
__global__ __launch_bounds__(256) void q_kernel(
    const float* __restrict__ q_emb, const float* __restrict__ Wq,
    const float* __restrict__ bq, u16* __restrict__ qout)
{
    __shared__ float sq[768];
    int b = blockIdx.y;
    int col = blockIdx.x * 256 + threadIdx.x;
    for (int i = threadIdx.x; i < 768; i += 256) sq[i] = q_emb[b * 768 + i];
    __syncthreads();
    float acc = 0.f;
    #pragma unroll 4
    for (int k = 0; k < 768; ++k) acc = fmaf(sq[k], Wq[(size_t)k * 1024 + col], acc);
    qout[b * 1024 + col] = f2bf(geluf(acc + bq[col]));
}

// ---------- qw1[bh][col] = q[bh,:] @ W1[0:128, col] + b1[col]   (f32 [512][256])
__global__ __launch_bounds__(256) void qw1_kernel(
    const u16* __restrict__ qbuf, const float* __restrict__ W1,
    const float* __restrict__ b1, float* __restrict__ qw1)
{
    __shared__ float sq[128];
    int bh = blockIdx.x;
    int col = threadIdx.x;
    if (col < 128) sq[col] = bf2f(qbuf[bh * 128 + col]);
    __syncthreads();
    float acc = b1[col];
    #pragma unroll 4
    for (int d = 0; d < 128; ++d) acc = fmaf(sq[d], W1[d * 256 + col], acc);
    qw1[bh * 256 + col] = acc;
}

// ---------- kgemm3: k = gelu(nf @ Wk + bk); writes [k, |q-k|, q*k] blocked tiles
// rows' = b*1024 + h*128 + n ; tiles [rt*12 + f*4 + dtt][64][32] swizzled
__global__ __launch_bounds__(256) void kgemm3(
    const u16* __restrict__ gA, const u16* __restrict__ gB,
    const float* __restrict__ bias, const u16* __restrict__ qbuf,
    u16* __restrict__ kblk3)
{
    __shared__ __attribute__((aligned(16))) u16 sm[16384];   // 32KB: As0 As1 Bs0 Bs1 / trans
    const int tid = threadIdx.x, lane = tid & 63, w = tid >> 6;
    const int lr = lane & 15, g = lane >> 4;
    const int wr = w >> 1, wc = w & 1;
    const int nb = blockIdx.x, mb = blockIdx.y;   // nb = h (0..7), mb = b (0..63)
    const int NT = 24;
    f32x4 acc[4][4];
    #pragma unroll
    for (int i = 0; i < 4; ++i)
        #pragma unroll
        for (int j = 0; j < 4; ++j) acc[i][j] = (f32x4){0.f, 0.f, 0.f, 0.f};

    auto stage = [&](int t, int bi) {
        #pragma unroll
        for (int c = w; c < 16; c += 4) {
            if (c < 8) async_copy16(gA + (size_t)(mb * 24 + t) * 4096 + c * 512 + lane * 8,
                                    sm + bi * 4096 + c * 512);
            else       async_copy16(gB + (size_t)(nb * 24 + t) * 4096 + (c - 8) * 512 + lane * 8,
                                    sm + 8192 + bi * 4096 + (c - 8) * 512);
        }
    };
    stage(0, 0);
    __syncthreads();
    for (int t = 0; t < NT; ++t) {
        int cur = t & 1;
        if (t + 1 < NT) stage(t + 1, cur ^ 1);
        const u16* A = sm + cur * 4096;
        const u16* B = sm + 8192 + cur * 4096;
        s16x8 bfr[4];
        #pragma unroll
        for (int j = 0; j < 4; ++j) bfr[j] = *(const s16x8*)&B[SWZ(wc * 64 + j * 16 + lr, g * 8)];
        #pragma unroll
        for (int i = 0; i < 4; ++i) {
            s16x8 a = *(const s16x8*)&A[SWZ(wr * 64 + i * 16 + lr, g * 8)];
            #pragma unroll
            for (int j = 0; j < 4; ++j) acc[i][j] = MFMA(a, bfr[j], acc[i][j]);
        }
        __syncthreads();
    }
    // epilogue: gelu(+bias) in place; features; LDS-transpose; coalesced store
    float qv[4], bv[4];
    #pragma unroll
    for (int j = 0; j < 4; ++j) {
        int d = wc * 64 + j * 16 + lr;
        qv[j] = bf2f(qbuf[mb * 1024 + nb * 128 + d]);
        bv[j] = bias[nb * 128 + d];
    }
    #pragma unroll
    for (int i = 0; i < 4; ++i)
        #pragma unroll
        for (int j = 0; j < 4; ++j) {
            f32x4 t = acc[i][j];
            #pragma unroll
            for (int r = 0; r < 4; ++r) t[r] = geluf(t[r] + bv[j]);
            acc[i][j] = t;
        }
    for (int f = 0; f < 3; ++f) {
        #pragma unroll
        for (int i = 0; i < 4; ++i)
            #pragma unroll
            for (int j = 0; j < 4; ++j) {
                int d = wc * 64 + j * 16 + lr;
                #pragma unroll
                for (int r = 0; r < 4; ++r) {
                    int row = wr * 64 + i * 16 + 4 * g + r;
                    float kv = acc[i][j][r];
                    float v = (f == 0) ? kv : (f == 1) ? fabsf(qv[j] - kv) : qv[j] * kv;
                    sm[(wr * 4 + (d >> 5)) * 2048 + SWZ(row & 63, KP(d & 31))] = f2bf(v);
                }
            }
        __syncthreads();
        for (int u = tid; u < 2048; u += 256) {
            int tile_id = u >> 8, wrh = tile_id >> 2, dtt = tile_id & 3;
            int rt = mb * 16 + nb * 2 + wrh;
            *(f32x4*)&kblk3[((size_t)(rt * 12 + f * 4 + dtt)) * 2048 + (size_t)(u & 255) * 8] =
                *(const f32x4*)&sm[u * 8];
        }
        __syncthreads();
    }
}

// ---------- h1gemm: pure GEMM A=kblk3 [rows' x 384] @ W1T [384 x 256]; +qW1 bias; gelu; LN; -> h2A
__global__ __launch_bounds__(256) void h1gemm(
    const u16* __restrict__ kblk3, const u16* __restrict__ w1t,
    const float* __restrict__ qw1, const float* __restrict__ g1v,
    const float* __restrict__ b1v, u16* __restrict__ h2A)
{
    __shared__ __attribute__((aligned(16))) u16 sm[24576];   // 48KB: As 2x8KB | Bs 2x16KB
    const int tid = threadIdx.x, lane = tid & 63, w = tid >> 6;   // w = col-slice 0..3
    const int lr = lane & 15, g = lane >> 4;
    const int mb = blockIdx.x;    // 0..511 : rows' [mb*128, +128) ; mb = b*8+h
    const int NT = 12;
    f32x4 acc[8][4];
    #pragma unroll
    for (int i = 0; i < 8; ++i)
        #pragma unroll
        for (int j = 0; j < 4; ++j) acc[i][j] = (f32x4){0.f, 0.f, 0.f, 0.f};

    auto stage = [&](int ks, int bi) {
        #pragma unroll
        for (int c = w; c < 24; c += 4) {
            if (c < 8)
                async_copy16(kblk3 + ((size_t)((2 * mb + (c >> 2)) * 12 + ks)) * 2048 + (c & 3) * 512 + lane * 8,
                             sm + bi * 4096 + c * 512);
            else
                async_copy16(w1t + (size_t)ks * 8192 + (c - 8) * 512 + lane * 8,
                             sm + 8192 + bi * 8192 + (c - 8) * 512);
        }
    };
    stage(0, 0);
    __syncthreads();
    for (int ks = 0; ks < NT; ++ks) {
        int cur = ks & 1;
        if (ks + 1 < NT) stage(ks + 1, cur ^ 1);
        const u16* A = sm + cur * 4096;
        const u16* B = sm + 8192 + cur * 8192;
        s16x8 bfr[4];
        #pragma unroll
        for (int j = 0; j < 4; ++j) bfr[j] = *(const s16x8*)&B[SWZ(w * 64 + j * 16 + lr, g * 8)];
        #pragma unroll
        for (int i = 0; i < 8; ++i) {
            s16x8 a = *(const s16x8*)&A[(i >> 2) * 2048 + SWZ((i * 16 + lr) & 63, g * 8)];
            #pragma unroll
            for (int j = 0; j < 4; ++j) acc[i][j] = MFMA(a, bfr[j], acc[i][j]);
        }
        __syncthreads();
    }
    // epilogue: + qW1 bias (b,h block-constant), gelu, LN over 256
    float qb[4], g1c[4], b1c[4];
    #pragma unroll
    for (int j = 0; j < 4; ++j) {
        int col = w * 64 + j * 16 + lr;
        qb[j] = qw1[(size_t)mb * 256 + col];
        g1c[j] = g1v[col]; b1c[j] = b1v[col];
    }
    #pragma unroll
    for (int i = 0; i < 8; ++i)
        #pragma unroll
        for (int j = 0; j < 4; ++j) {
            f32x4 t = acc[i][j];
            #pragma unroll
            for (int r = 0; r < 4; ++r) t[r] = geluf(t[r] + qb[j]);
            acc[i][j] = t;
        }
    float* part = (float*)sm;   // [128][4][2] f32 = 4KB (As region, dead)
    #pragma unroll
    for (int i = 0; i < 8; ++i)
        #pragma unroll
        for (int r = 0; r < 4; ++r) {
            float a = 0.f, bq = 0.f;
            #pragma unroll
            for (int j = 0; j < 4; ++j) { float v = acc[i][j][r]; a += v; bq += v * v; }
            #pragma unroll
            for (int m = 1; m <= 8; m <<= 1) { a += __shfl_xor(a, m, 64); bq += __shfl_xor(bq, m, 64); }
            if (lr == 0) {
                int row = i * 16 + 4 * g + r;
                part[(row * 4 + w) * 2 + 0] = a;
                part[(row * 4 + w) * 2 + 1] = bq;
            }
        }
    __syncthreads();
    #pragma unroll
    for (int i = 0; i < 8; ++i)
        #pragma unroll
        for (int r = 0; r < 4; ++r) {
            int row = i * 16 + 4 * g + r;
            float S  = part[row * 8] + part[row * 8 + 2] + part[row * 8 + 4] + part[row * 8 + 6];
            float S2 = part[row * 8 + 1] + part[row * 8 + 3] + part[row * 8 + 5] + part[row * 8 + 7];
            float mu = S * (1.f / 256.f);
            float var = S2 * (1.f / 256.f) - mu * mu;
            float rs = rsqrtf(var + 1e-5f);
            #pragma unroll
            for (int j = 0; j < 4; ++j)
                acc[i][j][r] = (acc[i][j][r] - mu) * rs * g1c[j] + b1c[j];
        }
    // two-pass LDS-transpose store (trans = Bs region, 32KB)
    u16* trans = sm + 8192;
    for (int p = 0; p < 2; ++p) {
        __syncthreads();
        #pragma unroll
        for (int ii = 0; ii < 4; ++ii) {
            int i = p * 4 + ii;
            #pragma unroll
            for (int j = 0; j < 4; ++j) {
                int col = w * 64 + j * 16 + lr;
                #pragma unroll
                for (int r = 0; r < 4; ++r) {
                    int row = i * 16 + 4 * g + r;
                    trans[(col >> 5) * 2048 + SWZ(row & 63, KP(col & 31))] = f2bf(acc[i][j][r]);
                }
            }
        }
        __syncthreads();
        for (int u = tid; u < 2048; u += 256)
            *(f32x4*)&h2A[((size_t)((2 * mb + p) * 8 + (u >> 8))) * 2048 + (size_t)(u & 255) * 8] =
                *(const f32x4*)&trans[u * 8];
    }
}

// ---------- h2gemm: h2A[65536x256] @ W2[256x128]; gelu + LN + dot(W3) -> scores f32 [b][h][n]
__global__ __launch_bounds__(256) void h2gemm(
    const u16* __restrict__ h2A, const u16* __restrict__ w2t,
    const float* __restrict__ b2v, const float* __restrict__ g2v,
    const float* __restrict__ bb2, const float* __restrict__ W3,
    const float* __restrict__ b3, float* __restrict__ scores)
{
    __shared__ __attribute__((aligned(16))) u16 sm[16384];   // As 2x8KB | Bs 2x8KB
    const int tid = threadIdx.x, lane = tid & 63, w = tid >> 6;
    const int lr = lane & 15, g = lane >> 4;
    const int wr = w >> 1, wc = w & 1;
    const int mb = blockIdx.x;   // 0..511
    const int NT = 8;
    f32x4 acc[4][4];
    #pragma unroll
    for (int i = 0; i < 4; ++i)
        #pragma unroll
        for (int j = 0; j < 4; ++j) acc[i][j] = (f32x4){0.f, 0.f, 0.f, 0.f};

    auto stage = [&](int t, int bi) {
        #pragma unroll
        for (int c = w; c < 16; c += 4) {
            if (c < 8)
                async_copy16(h2A + ((size_t)((2 * mb + (c >> 2)) * 8 + t)) * 2048 + (c & 3) * 512 + lane * 8,
                             sm + bi * 4096 + c * 512);
            else
                async_copy16(w2t + (size_t)t * 4096 + (c - 8) * 512 + lane * 8,
                             sm + 8192 + bi * 4096 + (c - 8) * 512);
        }
    };
    stage(0, 0);
    __syncthreads();
    for (int t = 0; t < NT; ++t) {
        int cur = t & 1;
        if (t + 1 < NT) stage(t + 1, cur ^ 1);
        const u16* A = sm + cur * 4096;
        const u16* B = sm + 8192 + cur * 4096;
        s16x8 bfr[4];
        #pragma unroll
        for (int j = 0; j < 4; ++j) bfr[j] = *(const s16x8*)&B[SWZ(wc * 64 + j * 16 + lr, g * 8)];
        #pragma unroll
        for (int i = 0; i < 4; ++i) {
            s16x8 a = *(const s16x8*)&A[wr * 2048 + SWZ(i * 16 + lr, g * 8)];
            #pragma unroll
            for (int j = 0; j < 4; ++j) acc[i][j] = MFMA(a, bfr[j], acc[i][j]);
        }
        __syncthreads();
    }
    float bkc[4], g2c[4], b2c[4], w3c[4];
    #pragma unroll
    for (int j = 0; j < 4; ++j) {
        int col = wc * 64 + j * 16 + lr;
        bkc[j] = b2v[col]; g2c[j] = g2v[col]; b2c[j] = bb2[col]; w3c[j] = W3[col];
    }
    #pragma unroll
    for (int i = 0; i < 4; ++i)
        #pragma unroll
        for (int j = 0; j < 4; ++j) {
            f32x4 t = acc[i][j];
            #pragma unroll
            for (int r = 0; r < 4; ++r) t[r] = geluf(t[r] + bkc[j]);
            acc[i][j] = t;
        }
    float* part = (float*)sm;          // [128][2][2]
    float* dotb = (float*)(sm + 1024); // [128][2]
    #pragma unroll
    for (int i = 0; i < 4; ++i)
        #pragma unroll
        for (int r = 0; r < 4; ++r) {
            float a = 0.f, bq = 0.f;
            #pragma unroll
            for (int j = 0; j < 4; ++j) { float v = acc[i][j][r]; a += v; bq += v * v; }
            #pragma unroll
            for (int m = 1; m <= 8; m <<= 1) { a += __shfl_xor(a, m, 64); bq += __shfl_xor(bq, m, 64); }
            if (lr == 0) {
                int rl = wr * 64 + i * 16 + 4 * g + r;
                part[(rl * 2 + wc) * 2 + 0] = a;
                part[(rl * 2 + wc) * 2 + 1] = bq;
            }
        }
    __syncthreads();
    #pragma unroll
    for (int i = 0; i < 4; ++i)
        #pragma unroll
        for (int r = 0; r < 4; ++r) {
            int rl = wr * 64 + i * 16 + 4 * g + r;
            float S = part[rl * 4] + part[rl * 4 + 2];
            float S2 = part[rl * 4 + 1] + part[rl * 4 + 3];
            float mu = S * (1.f / 128.f);
            float var = S2 * (1.f / 128.f) - mu * mu;
            float rs = rsqrtf(var + 1e-5f);
            float d = 0.f;
            #pragma unroll
            for (int j = 0; j < 4; ++j) {
                float ln = (acc[i][j][r] - mu) * rs * g2c[j] + b2c[j];
                d += ln * w3c[j];
            }
            #pragma unroll
            for (int m = 1; m <= 8; m <<= 1) d += __shfl_xor(d, m, 64);
            if (lr == 0) dotb[rl * 2 + wc] = d;
        }
    __syncthreads();
    if (tid < 128) scores[(size_t)mb * 128 + tid] = dotb[tid * 2] + dotb[tid * 2 + 1] + b3[0];
}

// ---------- out[b] = sigmoid( sum_{h,n} score*gate*mask / 8 ), scores ordered [b][h][n]
__global__ __launch_bounds__(256) void final_kernel(
    const float* __restrict__ scores, const float* __restrict__ idfs,
    const float* __restrict__ mask, const float* __restrict__ gate_w,
    const float* __restrict__ gate_b, float* __restrict__ outp)
{
    int b = blockIdx.x, tid = threadIdx.x;
    float gw = gate_w[0], gb = gate_b[0];
    float acc = 0.f;
    for (int i = tid; i < 1024; i += 256) {
        int n = i & 127;
        float lg = log1pf(idfs[b * 128 + n]);
        float gate = 1.f / (1.f + expf(-(lg * gw + gb)));
        acc += scores[b * 1024 + i] * gate * mask[b * 128 + n];
    }
    acc = wave_reduce_sum(acc);
    __shared__ float wsum[4];
    if ((tid & 63) == 0) wsum[tid >> 6] = acc;
    __syncthreads();
    if (tid == 0) {
        float t = wsum[0] + wsum[1] + wsum[2] + wsum[3];
        outp[b] = 1.f / (1.f + expf(-t * 0.125f));
    }
}

extern "C" void kernel_launch(void* const* d_in, const int* in_sizes, int n_in,
                              void* d_out, int out_size, void* d_ws, size_t ws_size,
                              hipStream_t stream) {
    const float* q_emb    = (const float*)d_in[0];
    const float* ent      = (const float*)d_in[1];
    const int*   roles    = (const int*)d_in[2];
    const float* idfs     = (const float*)d_in[3];
    const float* mask     = (const float*)d_in[4];
    const float* role_emb = (const float*)d_in[5];
    const float* ln_f_g   = (const float*)d_in[6];
    const float* ln_f_b   = (const float*)d_in[7];
    const float* Wq       = (const float*)d_in[8];
    const float* bq       = (const float*)d_in[9];
    const float* Wk       = (const float*)d_in[10];
    const float* bk       = (const float*)d_in[11];
    const float* W1       = (const float*)d_in[12];
    const float* b1       = (const float*)d_in[13];
    const float* ln1_g    = (const float*)d_in[14];
    const float* ln1_b    = (const float*)d_in[15];
    const float* W2       = (const float*)d_in[16];
    const float* b2       = (const float*)d_in[17];
    const float* ln2_g    = (const float*)d_in[18];
    const float* ln2_b    = (const float*)d_in[19];
    const float* W3       = (const float*)d_in[20];
    const float* b3       = (const float*)d_in[21];
    const float* gate_w   = (const float*)d_in[22];
    const float* gate_b   = (const float*)d_in[23];
    float* outp = (float*)d_out;

    // workspace layout (bytes), disjoint; peak ~99.2 MB
    char* ws = (char*)d_ws;
    u16*   nfb    = (u16*)(ws);                          // 12,582,912
    u16*   kblk3  = (u16*)(ws + (size_t)12582912);       // 50,331,648
    u16*   h2A    = (u16*)(ws + (size_t)62914560);       // 33,554,432
    u16*   WkT    = (u16*)(ws + (size_t)96468992);       //  1,572,864
    u16*   W1T    = (u16*)(ws + (size_t)98041856);       //    196,608
    u16*   W2T    = (u16*)(ws + (size_t)98238464);       //     65,536
    u16*   qbuf   = (u16*)(ws + (size_t)98304000);       //    131,072
    float* qw1    = (float*)(ws + (size_t)98435072);     //    524,288
    float* scores = (float*)(ws + (size_t)98959360);     //    262,144

    prep_w<<<3072, 256, 0, stream>>>(Wk, WkT, 768, 1024, 128);
    prep_w<<<128, 256, 0, stream>>>(W2, W2T, 256, 128, 128);
    prep_w1<<<384, 256, 0, stream>>>(W1, W1T);
    nf_ln_kernel<<<2048, 256, 0, stream>>>(ent, roles, role_emb, ln_f_g, ln_f_b, nfb);
    q_kernel<<<dim3(4, 64), 256, 0, stream>>>(q_emb, Wq, bq, qbuf);
    qw1_kernel<<<512, 256, 0, stream>>>(qbuf, W1, b1, qw1);
    kgemm3<<<dim3(8, 64), 256, 0, stream>>>(nfb, WkT, bk, qbuf, kblk3);
    h1gemm<<<512, 256, 0, stream>>>(kblk3, W1T, qw1, ln1_g, ln1_b, h2A);
    h2gemm<<<512, 256, 0, stream>>>(h2A, W2T, b2, ln2_g, ln2_b, W3, b3, scores);
    final_kernel<<<64, 256, 0, stream>>>(scores, idfs, mask, gate_w, gate_b, outp);
}

// Round 5
// 364.464 us; speedup vs baseline: 1.2978x; 1.2978x over previous
//
#include <hip/hip_runtime.h>
#include <hip/hip_bf16.h>
#include <math.h>

typedef unsigned short u16;
typedef short s16x8 __attribute__((ext_vector_type(8)));
typedef float f32x4 __attribute__((ext_vector_type(4)));

// k-interleave within a 32-wide k-tile: lane group g reads contiguous 16B =
// k [4g..4g+3, 16+4g..16+4g+3]
__device__ __host__ __forceinline__ int KP(int k) {
    return ((k & 12) << 1) | (((k >> 4) & 1) << 2) | (k & 3);
}

__device__ __forceinline__ float geluf(float x) {
    return 0.5f * x * (1.0f + erff(x * 0.70710678118654752f));
}
__device__ __forceinline__ u16 f2bf(float f) {
    unsigned u = __builtin_bit_cast(unsigned, f);
    return (u16)((u + 0x7fffu + ((u >> 16) & 1u)) >> 16);
}
__device__ __forceinline__ float bf2f(u16 h) {
    return __builtin_bit_cast(float, ((unsigned)h) << 16);
}
__device__ __forceinline__ void async_copy16(const u16* gsrc, u16* ldst) {
    __builtin_amdgcn_global_load_lds((const __attribute__((address_space(1))) void*)gsrc,
                                     (__attribute__((address_space(3))) void*)ldst, 16, 0, 0);
}
__device__ __forceinline__ float wave_reduce_sum(float v) {
    #pragma unroll
    for (int m = 32; m >= 1; m >>= 1) v += __shfl_xor(v, m, 64);
    return v;
}

#define MFMA(a, b, c) __builtin_amdgcn_mfma_f32_16x16x32_bf16(a, b, c, 0, 0, 0)

// ---------- prep: W[K][N] fp32 -> blocked bf16 tiles [(cb*K/32+kt)][CB rows][32] (KP order)
__global__ __launch_bounds__(256) void prep_w(const float* __restrict__ W, u16* __restrict__ out,
                                              int K, int N, int CB) {
    int idx = blockIdx.x * 256 + threadIdx.x;
    if (idx >= K * N) return;
    int k = idx / N, col = idx % N;
    int cb = col / CB, ci = col % CB, kt = k >> 5, ki = k & 31;
    out[(size_t)(cb * (K >> 5) + kt) * (CB * 32) + ci * 32 + KP(ki)] = f2bf(W[idx]);
}

// ---------- nf = LN(ent + role_emb[roles]) -> blocked bf16 tiles [(row>>7)*24+kt][128][32]
__global__ __launch_bounds__(256) void nf_ln_kernel(
    const float* __restrict__ ent, const int* __restrict__ roles,
    const float* __restrict__ role_emb, const float* __restrict__ g,
    const float* __restrict__ bta, u16* __restrict__ nfb)
{
    int wave = threadIdx.x >> 6, lane = threadIdx.x & 63;
    int row = blockIdx.x * 4 + wave;
    const float* er = ent + (size_t)row * 768;
    const float* rr = role_emb + roles[row] * 768;
    float x[12]; float s = 0.f, s2 = 0.f;
    #pragma unroll
    for (int i = 0; i < 12; ++i) {
        x[i] = er[i * 64 + lane] + rr[i * 64 + lane];
        s += x[i]; s2 += x[i] * x[i];
    }
    s = wave_reduce_sum(s); s2 = wave_reduce_sum(s2);
    float mu = s * (1.f / 768.f);
    float var = s2 * (1.f / 768.f) - mu * mu;
    float rs = rsqrtf(var + 1e-5f);
    size_t rb = (size_t)(row >> 7) * 24;
    int rin = row & 127;
    #pragma unroll
    for (int i = 0; i < 12; ++i) {
        int k = i * 64 + lane;
        float v = (x[i] - mu) * rs * g[k] + bta[k];
        nfb[(rb + (k >> 5)) * 4096 + rin * 32 + KP(k & 31)] = f2bf(v);
    }
}

// ---------- q = gelu(q_emb @ Wq + bq) -> bf16 [64][1024] row-major
__global__ __launch_bounds__(256) void q_kernel(
    const float* __restrict__ q_emb, const float* __restrict__ Wq,
    const float* __restrict__ bq, u16* __restrict__ qout)
{
    __shared__ float sq[768];
    int b = blockIdx.y;
    int col = blockIdx.x * 256 + threadIdx.x;
    for (int i = threadIdx.x; i < 768; i += 256) sq[i] = q_emb[b * 768 + i];
    __syncthreads();
    float acc = 0.f;
    #pragma unroll 4
    for (int k = 0; k < 768; ++k) acc = fmaf(sq[k], Wq[(size_t)k * 1024 + col], acc);
    qout[b * 1024 + col] = f2bf(geluf(acc + bq[col]));
}

// ---------- kgemm: nf[8192x768] @ Wk[768x1024] + gelu -> kbuf bf16 row-major [8192][1024]
// m97 shape: 128x128 tile, 256 thr, 4 waves 2x2, acc[4][4], NT=24, 32KB LDS dbuf
__global__ __launch_bounds__(256) void kgemm(
    const u16* __restrict__ gA, const u16* __restrict__ gB,
    const float* __restrict__ bias, u16* __restrict__ kbuf)
{
    __shared__ __attribute__((aligned(16))) u16 As[2][4096];
    __shared__ __attribute__((aligned(16))) u16 Bs[2][4096];
    const int tid = threadIdx.x, lane = tid & 63, w = tid >> 6;
    const int lr = lane & 15, g = lane >> 4;
    const int wr = w >> 1, wc = w & 1;
    const int nb = blockIdx.x, mb = blockIdx.y;   // 8 x 64
    const int NT = 24;
    f32x4 acc[4][4];
    #pragma unroll
    for (int i = 0; i < 4; ++i)
        #pragma unroll
        for (int j = 0; j < 4; ++j) acc[i][j] = (f32x4){0.f, 0.f, 0.f, 0.f};

    auto stage = [&](int t, int bi) {
        #pragma unroll
        for (int i = 0; i < 2; ++i) {
            int c = w * 2 + i;   // 0..7
            async_copy16(gA + (size_t)(mb * 24 + t) * 4096 + c * 512 + lane * 8, As[bi] + c * 512);
            async_copy16(gB + (size_t)(nb * 24 + t) * 4096 + c * 512 + lane * 8, Bs[bi] + c * 512);
        }
    };
    stage(0, 0);
    __syncthreads();
    for (int t = 0; t < NT; ++t) {
        int cur = t & 1;
        if (t + 1 < NT) stage(t + 1, cur ^ 1);
        s16x8 bfr[4];
        #pragma unroll
        for (int j = 0; j < 4; ++j) bfr[j] = *(const s16x8*)&Bs[cur][(wc * 64 + j * 16 + lr) * 32 + g * 8];
        #pragma unroll
        for (int i = 0; i < 4; ++i) {
            s16x8 a = *(const s16x8*)&As[cur][(wr * 64 + i * 16 + lr) * 32 + g * 8];
            #pragma unroll
            for (int j = 0; j < 4; ++j) acc[i][j] = MFMA(a, bfr[j], acc[i][j]);
        }
        __syncthreads();
    }
    float bv[4];
    #pragma unroll
    for (int j = 0; j < 4; ++j) bv[j] = bias[nb * 128 + wc * 64 + j * 16 + lr];
    #pragma unroll
    for (int i = 0; i < 4; ++i)
        #pragma unroll
        for (int r = 0; r < 4; ++r) {
            int row = mb * 128 + wr * 64 + i * 16 + 4 * g + r;
            #pragma unroll
            for (int j = 0; j < 4; ++j) {
                int col = nb * 128 + wc * 64 + j * 16 + lr;
                kbuf[(size_t)row * 1024 + col] = f2bf(geluf(acc[i][j][r] + bv[j]));
            }
        }
}

// ---------- h1gemm: interaction[65536x512] @ W1[512x256] built in staging; +b1, gelu, LN -> h2A
// BM=64, BN=256 (full row), 256 thr, 4 waves (col slices), acc[4][4], NT=16
// rows' = (b*128+n)*8+h. Feature block f = t>>2: 0=q, 1=k, 2=|q-k|, 3=q*k
__global__ __launch_bounds__(256) void h1gemm(
    const u16* __restrict__ kbuf, const u16* __restrict__ qbuf,
    const u16* __restrict__ w1t, const float* __restrict__ b1v,
    const float* __restrict__ g1v, const float* __restrict__ bb1,
    u16* __restrict__ h2A)
{
    __shared__ __attribute__((aligned(16))) u16 As[2][2048];
    __shared__ __attribute__((aligned(16))) u16 Bs[2][8192];
    __shared__ float part[64][4][2];
    const int tid = threadIdx.x, lane = tid & 63, w = tid >> 6;   // w = col slice 0..3
    const int lr = lane & 15, g = lane >> 4;
    const int mb = blockIdx.x;                 // 0..1023, rows' [mb*64, +64)
    const int rl = tid >> 2, gq = tid & 3;     // staging: row-in-tile, k-group
    const int srow = mb * 64 + rl;
    const int sh = srow & 7;
    const size_t koff = (size_t)(srow >> 3) * 1024 + sh * 128;   // kbuf row (b*128+n), col h*128+
    const int qoff = (srow >> 10) * 1024 + sh * 128;
    const int NT = 16;
    f32x4 acc[4][4];
    #pragma unroll
    for (int i = 0; i < 4; ++i)
        #pragma unroll
        for (int j = 0; j < 4; ++j) acc[i][j] = (f32x4){0.f, 0.f, 0.f, 0.f};

    auto stageB = [&](int t, int bi) {
        #pragma unroll
        for (int i = 0; i < 4; ++i) {
            int c = w * 4 + i;   // 0..15
            async_copy16(w1t + (size_t)t * 8192 + c * 512 + lane * 8, Bs[bi] + c * 512);
        }
    };
    auto loadA = [&](int t, ushort4* kv, ushort4* qv) {
        int f = t >> 2, dd = (t & 3) * 32 + gq * 4;
        if (f != 0) {
            kv[0] = *(const ushort4*)&kbuf[koff + dd];
            kv[1] = *(const ushort4*)&kbuf[koff + dd + 16];
        }
        if (f != 1) {
            qv[0] = *(const ushort4*)&qbuf[qoff + dd];
            qv[1] = *(const ushort4*)&qbuf[qoff + dd + 16];
        }
    };
    auto writeA = [&](int t, int bi, const ushort4* kv, const ushort4* qv) {
        int f = t >> 2;
        u16 o[8];
        #pragma unroll
        for (int hf = 0; hf < 2; ++hf) {
            const u16* kp = (const u16*)&kv[hf];
            const u16* qp = (const u16*)&qv[hf];
            #pragma unroll
            for (int e = 0; e < 4; ++e) {
                u16 r;
                if (f == 0)      r = qp[e];
                else if (f == 1) r = kp[e];
                else if (f == 2) r = f2bf(fabsf(bf2f(qp[e]) - bf2f(kp[e])));
                else             r = f2bf(bf2f(qp[e]) * bf2f(kp[e]));
                o[hf * 4 + e] = r;
            }
        }
        *(s16x8*)&As[bi][rl * 32 + gq * 8] = *(const s16x8*)o;
    };

    {
        ushort4 kv[2] = {}, qv[2] = {};
        loadA(0, kv, qv);
        writeA(0, 0, kv, qv);
        stageB(0, 0);
    }
    __syncthreads();
    for (int t = 0; t < NT; ++t) {
        int cur = t & 1;
        ushort4 kv[2] = {}, qv[2] = {};
        if (t + 1 < NT) {
            loadA(t + 1, kv, qv);      // issue global loads (reg) early
            stageB(t + 1, cur ^ 1);    // issue B global_load_lds
        }
        s16x8 bfr[4];
        #pragma unroll
        for (int j = 0; j < 4; ++j) bfr[j] = *(const s16x8*)&Bs[cur][(w * 64 + j * 16 + lr) * 32 + g * 8];
        #pragma unroll
        for (int i = 0; i < 4; ++i) {
            s16x8 a = *(const s16x8*)&As[cur][(i * 16 + lr) * 32 + g * 8];
            #pragma unroll
            for (int j = 0; j < 4; ++j) acc[i][j] = MFMA(a, bfr[j], acc[i][j]);
        }
        if (t + 1 < NT) writeA(t + 1, cur ^ 1, kv, qv);   // ds_write after MFMA (T14)
        __syncthreads();
    }
    // epilogue: +b1, gelu, LN over 256, blocked store for h2
    float bc[4], g1c[4], b1c[4];
    #pragma unroll
    for (int j = 0; j < 4; ++j) {
        int col = w * 64 + j * 16 + lr;
        bc[j] = b1v[col]; g1c[j] = g1v[col]; b1c[j] = bb1[col];
    }
    #pragma unroll
    for (int i = 0; i < 4; ++i)
        #pragma unroll
        for (int j = 0; j < 4; ++j) {
            f32x4 tt = acc[i][j];
            #pragma unroll
            for (int r = 0; r < 4; ++r) tt[r] = geluf(tt[r] + bc[j]);
            acc[i][j] = tt;
        }
    #pragma unroll
    for (int i = 0; i < 4; ++i)
        #pragma unroll
        for (int r = 0; r < 4; ++r) {
            float a = 0.f, bsq = 0.f;
            #pragma unroll
            for (int j = 0; j < 4; ++j) { float v = acc[i][j][r]; a += v; bsq += v * v; }
            #pragma unroll
            for (int m = 1; m <= 8; m <<= 1) { a += __shfl_xor(a, m, 64); bsq += __shfl_xor(bsq, m, 64); }
            if (lr == 0) {
                int r2 = i * 16 + 4 * g + r;
                part[r2][w][0] = a; part[r2][w][1] = bsq;
            }
        }
    __syncthreads();
    #pragma unroll
    for (int i = 0; i < 4; ++i)
        #pragma unroll
        for (int r = 0; r < 4; ++r) {
            int r2 = i * 16 + 4 * g + r;
            float S  = part[r2][0][0] + part[r2][1][0] + part[r2][2][0] + part[r2][3][0];
            float S2 = part[r2][0][1] + part[r2][1][1] + part[r2][2][1] + part[r2][3][1];
            float mu = S * (1.f / 256.f);
            float var = S2 * (1.f / 256.f) - mu * mu;
            float rs = rsqrtf(var + 1e-5f);
            int row_g = mb * 64 + r2;
            size_t base = ((size_t)(row_g >> 7) * 8) * 4096 + (size_t)(row_g & 127) * 32;
            #pragma unroll
            for (int j = 0; j < 4; ++j) {
                int col = w * 64 + j * 16 + lr;
                float ln = (acc[i][j][r] - mu) * rs * g1c[j] + b1c[j];
                h2A[base + (size_t)(col >> 5) * 4096 + KP(col & 31)] = f2bf(ln);
            }
        }
}

// ---------- h2gemm: h2A[65536x256] @ W2[256x128]; gelu + LN + dot(W3) -> scores f32 [rows']
__global__ __launch_bounds__(256) void h2gemm(
    const u16* __restrict__ h2A, const u16* __restrict__ w2t,
    const float* __restrict__ b2v, const float* __restrict__ g2v,
    const float* __restrict__ bb2, const float* __restrict__ W3,
    const float* __restrict__ b3, float* __restrict__ scores)
{
    __shared__ __attribute__((aligned(16))) u16 As[2][4096];
    __shared__ __attribute__((aligned(16))) u16 Bs[2][4096];
    __shared__ float part[128][2][2];
    __shared__ float dotb[128][2];
    const int tid = threadIdx.x, lane = tid & 63, w = tid >> 6;
    const int lr = lane & 15, g = lane >> 4;
    const int wr = w >> 1, wc = w & 1;
    const int mb = blockIdx.x;   // 0..511
    const int NT = 8;
    f32x4 acc[4][4];
    #pragma unroll
    for (int i = 0; i < 4; ++i)
        #pragma unroll
        for (int j = 0; j < 4; ++j) acc[i][j] = (f32x4){0.f, 0.f, 0.f, 0.f};

    auto stage = [&](int t, int bi) {
        #pragma unroll
        for (int i = 0; i < 2; ++i) {
            int c = w * 2 + i;
            async_copy16(h2A + (size_t)(mb * 8 + t) * 4096 + c * 512 + lane * 8, As[bi] + c * 512);
            async_copy16(w2t + (size_t)t * 4096 + c * 512 + lane * 8, Bs[bi] + c * 512);
        }
    };
    stage(0, 0);
    __syncthreads();
    for (int t = 0; t < NT; ++t) {
        int cur = t & 1;
        if (t + 1 < NT) stage(t + 1, cur ^ 1);
        s16x8 bfr[4];
        #pragma unroll
        for (int j = 0; j < 4; ++j) bfr[j] = *(const s16x8*)&Bs[cur][(wc * 64 + j * 16 + lr) * 32 + g * 8];
        #pragma unroll
        for (int i = 0; i < 4; ++i) {
            s16x8 a = *(const s16x8*)&As[cur][(wr * 64 + i * 16 + lr) * 32 + g * 8];
            #pragma unroll
            for (int j = 0; j < 4; ++j) acc[i][j] = MFMA(a, bfr[j], acc[i][j]);
        }
        __syncthreads();
    }
    float bkc[4], g2c[4], b2c[4], w3c[4];
    #pragma unroll
    for (int j = 0; j < 4; ++j) {
        int col = wc * 64 + j * 16 + lr;
        bkc[j] = b2v[col]; g2c[j] = g2v[col]; b2c[j] = bb2[col]; w3c[j] = W3[col];
    }
    #pragma unroll
    for (int i = 0; i < 4; ++i)
        #pragma unroll
        for (int j = 0; j < 4; ++j) {
            f32x4 tt = acc[i][j];
            #pragma unroll
            for (int r = 0; r < 4; ++r) tt[r] = geluf(tt[r] + bkc[j]);
            acc[i][j] = tt;
        }
    #pragma unroll
    for (int i = 0; i < 4; ++i)
        #pragma unroll
        for (int r = 0; r < 4; ++r) {
            float a = 0.f, bsq = 0.f;
            #pragma unroll
            for (int j = 0; j < 4; ++j) { float v = acc[i][j][r]; a += v; bsq += v * v; }
            #pragma unroll
            for (int m = 1; m <= 8; m <<= 1) { a += __shfl_xor(a, m, 64); bsq += __shfl_xor(bsq, m, 64); }
            if (lr == 0) {
                int rl = wr * 64 + i * 16 + 4 * g + r;
                part[rl][wc][0] = a; part[rl][wc][1] = bsq;
            }
        }
    __syncthreads();
    #pragma unroll
    for (int i = 0; i < 4; ++i)
        #pragma unroll
        for (int r = 0; r < 4; ++r) {
            int rl = wr * 64 + i * 16 + 4 * g + r;
            float S = part[rl][0][0] + part[rl][1][0];
            float S2 = part[rl][0][1] + part[rl][1][1];
            float mu = S * (1.f / 128.f);
            float var = S2 * (1.f / 128.f) - mu * mu;
            float rs = rsqrtf(var + 1e-5f);
            float d = 0.f;
            #pragma unroll
            for (int j = 0; j < 4; ++j) {
                float ln = (acc[i][j][r] - mu) * rs * g2c[j] + b2c[j];
                d += ln * w3c[j];
            }
            #pragma unroll
            for (int m = 1; m <= 8; m <<= 1) d += __shfl_xor(d, m, 64);
            if (lr == 0) dotb[rl][wc] = d;
        }
    __syncthreads();
    if (tid < 128) scores[(size_t)mb * 128 + tid] = dotb[tid][0] + dotb[tid][1] + b3[0];
}

// ---------- out[b] = sigmoid( sum_{n,h} score*gate*mask / 8 ), scores rows' = (b*128+n)*8+h
__global__ __launch_bounds__(256) void final_kernel(
    const float* __restrict__ scores, const float* __restrict__ idfs,
    const float* __restrict__ mask, const float* __restrict__ gate_w,
    const float* __restrict__ gate_b, float* __restrict__ outp)
{
    int b = blockIdx.x, tid = threadIdx.x;
    float gw = gate_w[0], gb = gate_b[0];
    float acc = 0.f;
    for (int i = tid; i < 1024; i += 256) {
        int n = i >> 3;
        float lg = log1pf(idfs[b * 128 + n]);
        float gate = 1.f / (1.f + expf(-(lg * gw + gb)));
        acc += scores[b * 1024 + i] * gate * mask[b * 128 + n];
    }
    acc = wave_reduce_sum(acc);
    __shared__ float wsum[4];
    if ((tid & 63) == 0) wsum[tid >> 6] = acc;
    __syncthreads();
    if (tid == 0) {
        float t = wsum[0] + wsum[1] + wsum[2] + wsum[3];
        outp[b] = 1.f / (1.f + expf(-t * 0.125f));
    }
}

extern "C" void kernel_launch(void* const* d_in, const int* in_sizes, int n_in,
                              void* d_out, int out_size, void* d_ws, size_t ws_size,
                              hipStream_t stream) {
    const float* q_emb    = (const float*)d_in[0];
    const float* ent      = (const float*)d_in[1];
    const int*   roles    = (const int*)d_in[2];
    const float* idfs     = (const float*)d_in[3];
    const float* mask     = (const float*)d_in[4];
    const float* role_emb = (const float*)d_in[5];
    const float* ln_f_g   = (const float*)d_in[6];
    const float* ln_f_b   = (const float*)d_in[7];
    const float* Wq       = (const float*)d_in[8];
    const float* bq       = (const float*)d_in[9];
    const float* Wk       = (const float*)d_in[10];
    const float* bk       = (const float*)d_in[11];
    const float* W1       = (const float*)d_in[12];
    const float* b1       = (const float*)d_in[13];
    const float* ln1_g    = (const float*)d_in[14];
    const float* ln1_b    = (const float*)d_in[15];
    const float* W2       = (const float*)d_in[16];
    const float* b2       = (const float*)d_in[17];
    const float* ln2_g    = (const float*)d_in[18];
    const float* ln2_b    = (const float*)d_in[19];
    const float* W3       = (const float*)d_in[20];
    const float* b3       = (const float*)d_in[21];
    const float* gate_w   = (const float*)d_in[22];
    const float* gate_b   = (const float*)d_in[23];
    float* outp = (float*)d_out;

    // workspace layout (bytes), disjoint; peak ~65.2 MB
    char* ws = (char*)d_ws;
    u16*   nfb    = (u16*)(ws);                          // 12,582,912
    u16*   kbuf   = (u16*)(ws + (size_t)12582912);       // 16,777,216
    u16*   h2A    = (u16*)(ws + (size_t)29360128);       // 33,554,432
    u16*   WkT    = (u16*)(ws + (size_t)62914560);       //  1,572,864
    u16*   W1T    = (u16*)(ws + (size_t)64487424);       //    262,144
    u16*   W2T    = (u16*)(ws + (size_t)64749568);       //     65,536
    u16*   qbuf   = (u16*)(ws + (size_t)64815104);       //    131,072
    float* scores = (float*)(ws + (size_t)64946176);     //    262,144

    prep_w<<<3072, 256, 0, stream>>>(Wk, WkT, 768, 1024, 128);
    prep_w<<<512, 256, 0, stream>>>(W1, W1T, 512, 256, 256);
    prep_w<<<128, 256, 0, stream>>>(W2, W2T, 256, 128, 128);
    nf_ln_kernel<<<2048, 256, 0, stream>>>(ent, roles, role_emb, ln_f_g, ln_f_b, nfb);
    q_kernel<<<dim3(4, 64), 256, 0, stream>>>(q_emb, Wq, bq, qbuf);
    kgemm<<<dim3(8, 64), 256, 0, stream>>>(nfb, WkT, bk, kbuf);
    h1gemm<<<1024, 256, 0, stream>>>(kbuf, qbuf, W1T, b1, ln1_g, ln1_b, h2A);
    h2gemm<<<512, 256, 0, stream>>>(h2A, W2T, b2, ln2_g, ln2_b, W3, b3, scores);
    final_kernel<<<64, 256, 0, stream>>>(scores, idfs, mask, gate_w, gate_b, outp);
}